// Round 1
// baseline (788.159 us; speedup 1.0000x reference)
//
#include <hip/hip_runtime.h>
#include <cmath>

// out = (log(|DCT2(x)| + 1e-13) - mean) / std,  x: [384][256][256] f32.
// CORRECTNESS CONTRACT (R1-R3 evidence): reference accumulates in f32;
// near-zero DCT coefficients are f32 rounding NOISE and log() demands we
// reproduce that noise ~exactly. Every output element must be a single
// sequential fmaf chain, i ascending (stage 1) / j ascending (stage 2),
// with the stage-1 result rounded to f32. NO MFMA, NO split accumulators.
//
// R5: LDS-free restructure. R4's inner loop fed 64 FMA from 80 B of LDS
// (0.8 FMA/byte) -> LDS pipe saturates at ~51% VALUBusy. New scheme: per
// 1-wave block, one operand is wave-uniform (16 contiguous floats ->
// scalar s_load path, costs no VALU/LDS), the other is a lane-coalesced
// float4 from the L1/L2-resident 256KB basis. 64 FMA per 16 B/lane vload,
// zero LDS, zero barriers. Stage 1 writes the intermediate TRANSPOSED
// (T1t[j][k1]) so stage 2 gets the same structure with coalesced output.
// Numerics bit-identical to R4 (same chains, same epilogue).

#define HN    256
#define NIMG  384

// ---- f32 basis: Tdf[i][k] = (float)( cos(pi*(2i+1)*k/512) * s(k) ) --------
__global__ void basis_init(float* __restrict__ Tdf) {
    int idx = blockIdx.x * 256 + threadIdx.x;   // 65536
    int i = idx >> 8, k = idx & 255;
    double c = cos(M_PI * (2.0 * i + 1.0) * (double)k / 512.0);
    double s = (k == 0) ? sqrt(1.0 / 256.0) : sqrt(2.0 / 256.0);
    Tdf[idx] = (float)(c * s);
}

// 64 fmaf: acc[q] += A_q * B  (A_q scalar per q, B float4 per lane)
#define FMA_ROW(Q, AV, B) \
    acc[Q].x = fmaf(AV, B.x, acc[Q].x); \
    acc[Q].y = fmaf(AV, B.y, acc[Q].y); \
    acc[Q].z = fmaf(AV, B.z, acc[Q].z); \
    acc[Q].w = fmaf(AV, B.w, acc[Q].w);

#define FMA_ALL(B, C0, C1, C2, C3) \
    FMA_ROW( 0, C0.x, B) FMA_ROW( 1, C0.y, B) FMA_ROW( 2, C0.z, B) FMA_ROW( 3, C0.w, B) \
    FMA_ROW( 4, C1.x, B) FMA_ROW( 5, C1.y, B) FMA_ROW( 6, C1.z, B) FMA_ROW( 7, C1.w, B) \
    FMA_ROW( 8, C2.x, B) FMA_ROW( 9, C2.y, B) FMA_ROW(10, C2.z, B) FMA_ROW(11, C2.w, B) \
    FMA_ROW(12, C3.x, B) FMA_ROW(13, C3.y, B) FMA_ROW(14, C3.z, B) FMA_ROW(15, C3.w, B)

// ======================= two-kernel LDS-free path ==========================
// Stage 1: T1t[img][j][k1] = sum_i X[img][i][j] * Tdf[i][k1]   (i ascending)
// 1-wave block: 16 uniform j (s_load from X row) x 256 k1 across lanes
// (float4 from Tdf row, coalesced). acc[16]x4, stores coalesced.
__global__ __launch_bounds__(64, 4) void t1_kernel(
    const float* __restrict__ X, const float* __restrict__ Tdf,
    float* __restrict__ T1t)
{
    const int lane = threadIdx.x;            // k1 = 4*lane .. 4*lane+3
    const int img  = blockIdx.x >> 4;
    const int jb   = (blockIdx.x & 15) << 4; // 16-row j slab (block-uniform)
    const float* __restrict__ Xi = X + (size_t)img * (HN * HN);

    float4 acc[16];
    #pragma unroll
    for (int q = 0; q < 16; ++q) acc[q] = make_float4(0.f, 0.f, 0.f, 0.f);

    const float* __restrict__ bp = Tdf + 4 * lane;  // basis row i, this lane
    const float* __restrict__ ap = Xi + jb;         // X row i, uniform 64B

    float4 b  = *(const float4*)bp;
    float4 a0 = *(const float4*)(ap + 0);
    float4 a1 = *(const float4*)(ap + 4);
    float4 a2 = *(const float4*)(ap + 8);
    float4 a3 = *(const float4*)(ap + 12);

    #pragma unroll 1
    for (int i = 0; i < HN - 1; ++i) {
        const float4 cb = b;
        const float4 c0 = a0, c1 = a1, c2 = a2, c3 = a3;
        bp += HN; ap += HN;                  // prefetch i+1
        b  = *(const float4*)bp;
        a0 = *(const float4*)(ap + 0);
        a1 = *(const float4*)(ap + 4);
        a2 = *(const float4*)(ap + 8);
        a3 = *(const float4*)(ap + 12);
        FMA_ALL(cb, c0, c1, c2, c3);
    }
    FMA_ALL(b, a0, a1, a2, a3);              // i = 255

    // T1t[img][jb+q][4*lane .. +3]  (f32 intermediate, np-equal)
    float* __restrict__ T1i =
        T1t + (size_t)img * (HN * HN) + (size_t)jb * HN + 4 * lane;
    #pragma unroll
    for (int q = 0; q < 16; ++q)
        *(float4*)(T1i + q * HN) = acc[q];
}

// Stage 2: out[k1][k2] = sum_j T1t[j][k1] * Tdf[j][k2]   (j ascending) + epi
// 1-wave block: 16 uniform k1 (s_load from T1t row, contiguous thanks to
// transpose) x 256 k2 across lanes. Coalesced float4 output.
__global__ __launch_bounds__(64, 4) void y_kernel(
    const float* __restrict__ T1t, const float* __restrict__ Tdf,
    const float* __restrict__ meanp, const float* __restrict__ stdp,
    float* __restrict__ out)
{
    const int lane = threadIdx.x;            // k2 = 4*lane .. 4*lane+3
    const int img  = blockIdx.x >> 4;
    const int kb   = (blockIdx.x & 15) << 4; // 16-row k1 slab (block-uniform)
    const float* __restrict__ Ti = T1t + (size_t)img * (HN * HN);

    float4 acc[16];
    #pragma unroll
    for (int q = 0; q < 16; ++q) acc[q] = make_float4(0.f, 0.f, 0.f, 0.f);

    const float* __restrict__ bp = Tdf + 4 * lane;  // basis row j, this lane
    const float* __restrict__ ap = Ti + kb;         // T1t row j, uniform 64B

    float4 b  = *(const float4*)bp;
    float4 a0 = *(const float4*)(ap + 0);
    float4 a1 = *(const float4*)(ap + 4);
    float4 a2 = *(const float4*)(ap + 8);
    float4 a3 = *(const float4*)(ap + 12);

    #pragma unroll 1
    for (int j = 0; j < HN - 1; ++j) {
        const float4 cb = b;
        const float4 c0 = a0, c1 = a1, c2 = a2, c3 = a3;
        bp += HN; ap += HN;                  // prefetch j+1
        b  = *(const float4*)bp;
        a0 = *(const float4*)(ap + 0);
        a1 = *(const float4*)(ap + 4);
        a2 = *(const float4*)(ap + 8);
        a3 = *(const float4*)(ap + 12);
        FMA_ALL(cb, c0, c1, c2, c3);
    }
    FMA_ALL(b, a0, a1, a2, a3);              // j = 255

    const float mean = meanp[0];
    const float stdv = stdp[0];
    float* __restrict__ O =
        out + (size_t)img * (HN * HN) + (size_t)kb * HN + 4 * lane;
    #pragma unroll
    for (int q = 0; q < 16; ++q) {
        float4 v;
        v.x = (logf(fabsf(acc[q].x) + 1e-13f) - mean) / stdv;
        v.y = (logf(fabsf(acc[q].y) + 1e-13f) - mean) / stdv;
        v.z = (logf(fabsf(acc[q].z) + 1e-13f) - mean) / stdv;
        v.w = (logf(fabsf(acc[q].w) + 1e-13f) - mean) / stdv;
        *(float4*)(O + q * HN) = v;
    }
}

// ======================= fused fallback (R3, proven) =======================
#define SLAB 32
__global__ __launch_bounds__(256, 3) void dct2_f32(
    const float* __restrict__ X, const float* __restrict__ Tdf,
    const float* __restrict__ meanp, const float* __restrict__ stdp,
    float* __restrict__ out)
{
    __shared__ union SU {
        struct { float Xs[8][HN]; float CHc[8][SLAB]; } p1;
        float Bc[16][HN];
    } u;
    __shared__ float T1s[SLAB][HN + 1];

    const int t   = threadIdx.x;
    const int img = blockIdx.x >> 3;
    const int k0  = (blockIdx.x & 7) * SLAB;
    const float* __restrict__ Xi = X + (size_t)img * (HN * HN);
    const int ci = t & 7;
    const int ib = t >> 3;

    float acc[8][4];
    #pragma unroll
    for (int q = 0; q < 8; ++q)
        #pragma unroll
        for (int r = 0; r < 4; ++r) acc[q][r] = 0.0f;

    for (int i0 = 0; i0 < HN; i0 += 8) {
        {
            int rr = t >> 5, cc = (t & 31) * 4;
            float4 a = *(const float4*)(Xi + (i0 + rr) * HN + cc);
            float4 b = *(const float4*)(Xi + (i0 + rr) * HN + cc + 128);
            *(float4*)&u.p1.Xs[rr][cc]       = a;
            *(float4*)&u.p1.Xs[rr][cc + 128] = b;
            u.p1.CHc[rr][t & 31] = Tdf[(i0 + rr) * HN + k0 + (t & 31)];
        }
        __syncthreads();
        #pragma unroll
        for (int ii = 0; ii < 8; ++ii) {
            float xr[8];
            *(float4*)&xr[0] = *(const float4*)&u.p1.Xs[ii][8 * ib];
            *(float4*)&xr[4] = *(const float4*)&u.p1.Xs[ii][8 * ib + 4];
            float ch[4];
            *(float4*)&ch[0] = *(const float4*)&u.p1.CHc[ii][4 * ci];
            #pragma unroll
            for (int q = 0; q < 8; ++q)
                #pragma unroll
                for (int r = 0; r < 4; ++r)
                    acc[q][r] = fmaf(ch[r], xr[q], acc[q][r]);
        }
        __syncthreads();
    }
    #pragma unroll
    for (int q = 0; q < 8; ++q)
        #pragma unroll
        for (int r = 0; r < 4; ++r)
            T1s[4 * ci + r][8 * ib + q] = acc[q][r];
    __syncthreads();

    float acc2[8][4];
    #pragma unroll
    for (int q = 0; q < 8; ++q)
        #pragma unroll
        for (int r = 0; r < 4; ++r) acc2[q][r] = 0.0f;

    for (int j0 = 0; j0 < HN; j0 += 16) {
        #pragma unroll
        for (int rep = 0; rep < 4; ++rep) {
            int idx = rep * 1024 + t * 4;
            int p = idx >> 8, c = idx & 255;
            *(float4*)&u.Bc[p][c] = *(const float4*)(Tdf + (j0 + p) * HN + c);
        }
        __syncthreads();
        #pragma unroll
        for (int p = 0; p < 16; ++p) {
            float a[4];
            #pragma unroll
            for (int r = 0; r < 4; ++r) a[r] = T1s[4 * ci + r][j0 + p];
            float b[8];
            *(float4*)&b[0] = *(const float4*)&u.Bc[p][8 * ib];
            *(float4*)&b[4] = *(const float4*)&u.Bc[p][8 * ib + 4];
            #pragma unroll
            for (int q = 0; q < 8; ++q)
                #pragma unroll
                for (int r = 0; r < 4; ++r)
                    acc2[q][r] = fmaf(a[r], b[q], acc2[q][r]);
        }
        __syncthreads();
    }

    const float mean = meanp[0];
    const float stdv = stdp[0];
    #pragma unroll
    for (int q = 0; q < 8; ++q)
        #pragma unroll
        for (int r = 0; r < 4; ++r) {
            float v = (logf(fabsf(acc2[q][r]) + 1e-13f) - mean) / stdv;
            T1s[4 * ci + r][8 * ib + q] = v;
        }
    __syncthreads();

    float* __restrict__ O = out + (size_t)img * (HN * HN) + (size_t)k0 * HN;
    #pragma unroll
    for (int rep = 0; rep < 8; ++rep) {
        int idx = rep * 1024 + t * 4;
        int row = idx >> 8, col = idx & 255;
        float4 v = make_float4(T1s[row][col], T1s[row][col + 1],
                               T1s[row][col + 2], T1s[row][col + 3]);
        *(float4*)(O + row * HN + col) = v;
    }
}

extern "C" void kernel_launch(void* const* d_in, const int* in_sizes, int n_in,
                              void* d_out, int out_size, void* d_ws, size_t ws_size,
                              hipStream_t stream) {
    const float* X     = (const float*)d_in[0];
    const float* meanp = (const float*)d_in[1];
    const float* stdp  = (const float*)d_in[2];

    float* Tdf = (float*)d_ws;                       // 256 KB basis
    const size_t T1_OFF    = 256 * 1024;
    const size_t T1_BYTES  = (size_t)NIMG * HN * HN * sizeof(float);  // 100.7MB

    basis_init<<<256, 256, 0, stream>>>(Tdf);

    if (ws_size >= T1_OFF + T1_BYTES) {
        float* T1 = (float*)((char*)d_ws + T1_OFF);
        t1_kernel<<<NIMG * 16, 64, 0, stream>>>(X, Tdf, T1);
        y_kernel <<<NIMG * 16, 64, 0, stream>>>(T1, Tdf, meanp, stdp,
                                                (float*)d_out);
    } else {
        dct2_f32<<<NIMG * 8, 256, 0, stream>>>(X, Tdf, meanp, stdp,
                                               (float*)d_out);
    }
}

// Round 2
// 468.832 us; speedup vs baseline: 1.6811x; 1.6811x over previous
//
#include <hip/hip_runtime.h>
#include <cmath>

// out = (log(|DCT2(x)| + 1e-13) - mean) / std,  x: [384][256][256] f32.
// CORRECTNESS CONTRACT (R1-R3 evidence): reference accumulates in f32;
// near-zero DCT coefficients are f32 rounding NOISE and log() demands we
// reproduce that noise ~exactly. Every output element must be a single
// sequential fmaf chain, i ascending (stage 1) / j ascending (stage 2),
// with the stage-1 result rounded to f32. NO MFMA, NO split accumulators.
//
// R6: R5's LDS-free scheme was latency-dead (VALUBusy 15%) because the
// STREAMED operand (X, 100MB, HBM-cold) was the scalar one: 64B-per-1KB
// scatter reads, 1-deep prefetch, ~900cy misses. Swap roles:
//   vector operand (coalesced float4/lane) = the streamed array
//     stage1: X rows (contiguous streaming), stage2: basis rows (L1-hot)
//   scalar operand (s_load_dwordx16, wave-uniform 64B) = the warm array
//     stage1: basis (256KB, L2-resident), stage2: T1t (L3-warm)
// Stage 1 stores the intermediate TRANSPOSED (T1t[j][k1], in-register
// 16x4 transpose, scatter float4 stores once/wave) so stage 2's scalar
// operand is contiguous. readfirstlane(k1b) forces SMEM selection.
// Zero LDS, zero barriers, 64 v_fmac per {1 vmem + 1 smem}.
// Numerics bit-identical chains to the R4/R5 passing kernels.

#define HN    256
#define NIMG  384

// ---- f32 basis: Tdf[i][k] = (float)( cos(pi*(2i+1)*k/512) * s(k) ) --------
__global__ void basis_init(float* __restrict__ Tdf) {
    int idx = blockIdx.x * 256 + threadIdx.x;   // 65536
    int i = idx >> 8, k = idx & 255;
    double c = cos(M_PI * (2.0 * i + 1.0) * (double)k / 512.0);
    double s = (k == 0) ? sqrt(1.0 / 256.0) : sqrt(2.0 / 256.0);
    Tdf[idx] = (float)(c * s);
}

// blockIdx swizzle: the 4 blocks of one image land on the same XCD
// (HW round-robins consecutive workgroups across the 8 XCDs).
// n in [0,1536): img = (n%8)*48 + n/32  (0..383), kg = (n>>3)&3. Bijective.
__device__ __forceinline__ void decode_bx(int n, int& img, int& kg) {
    img = (n & 7) * 48 + (n >> 5);
    kg  = (n >> 3) & 3;
}

// 64 fmaf: acc[q].c += S[q] * V.c   (S scalar per q, V float4 per lane)
#define FMA16(S, V) \
    _Pragma("unroll") \
    for (int q = 0; q < 16; ++q) { \
        acc[q].x = fmaf(S[q], V.x, acc[q].x); \
        acc[q].y = fmaf(S[q], V.y, acc[q].y); \
        acc[q].z = fmaf(S[q], V.z, acc[q].z); \
        acc[q].w = fmaf(S[q], V.w, acc[q].w); \
    }

// ======================= two-kernel LDS-free path ==========================
// Stage 1: T1t[img][j][k1] = sum_i Tdf[i][k1] * X[img][i][j]   (i ascending)
// Block = 4 waves; wave w owns k1 slab [k1b, k1b+16), lanes span j (4/lane).
// Vector: X row i, float4/lane, coalesced streaming. Scalar: Tdf[i][k1b..+15].
__global__ __launch_bounds__(256, 4) void t1_kernel(
    const float* __restrict__ X, const float* __restrict__ Tdf,
    float* __restrict__ T1t)
{
    int img, kg; decode_bx(blockIdx.x, img, kg);
    const int wave = threadIdx.x >> 6;
    const int lane = threadIdx.x & 63;
    const int k1b  = __builtin_amdgcn_readfirstlane(kg * 64 + wave * 16);

    const float* __restrict__ xp = X + (size_t)img * (HN * HN) + 4 * lane;
    const float* __restrict__ bp = Tdf + k1b;

    float4 acc[16];
    #pragma unroll
    for (int q = 0; q < 16; ++q) acc[q] = make_float4(0.f, 0.f, 0.f, 0.f);

    float4 xv = *(const float4*)xp;
    float  bs[16];
    #pragma unroll
    for (int a = 0; a < 4; ++a)
        *(float4*)&bs[4 * a] = *(const float4*)(bp + 4 * a);

    #pragma unroll 1
    for (int i = 0; i < HN - 1; ++i) {
        const float4 xc = xv;
        float bc[16];
        #pragma unroll
        for (int q = 0; q < 16; ++q) bc[q] = bs[q];
        xp += HN; bp += HN;                  // prefetch row i+1
        xv = *(const float4*)xp;
        #pragma unroll
        for (int a = 0; a < 4; ++a)
            *(float4*)&bs[4 * a] = *(const float4*)(bp + 4 * a);
        FMA16(bc, xc);
    }
    FMA16(bs, xv);                           // i = 255

    // transposed store: T1t[img][4*lane+r][k1b + 4a + 0..3]
    float* __restrict__ T1o =
        T1t + (size_t)img * (HN * HN) + (size_t)(4 * lane) * HN + k1b;
    const float* af = (const float*)acc;     // af[4*q + r]
    #pragma unroll
    for (int r = 0; r < 4; ++r)
        #pragma unroll
        for (int a = 0; a < 4; ++a) {
            float4 v = make_float4(af[4 * (4 * a + 0) + r],
                                   af[4 * (4 * a + 1) + r],
                                   af[4 * (4 * a + 2) + r],
                                   af[4 * (4 * a + 3) + r]);
            *(float4*)(T1o + r * HN + 4 * a) = v;
        }
}

// Stage 2: out[k1][k2] = sum_j T1t[j][k1] * Tdf[j][k2]   (j ascending) + epi
// Block = 4 waves; wave w owns k1 slab [k1b, k1b+16), lanes span k2 (4/lane).
// Vector: Tdf row j (L1-hot). Scalar: T1t[img][j][k1b..+15] (64B contiguous).
__global__ __launch_bounds__(256, 4) void y_kernel(
    const float* __restrict__ T1t, const float* __restrict__ Tdf,
    const float* __restrict__ meanp, const float* __restrict__ stdp,
    float* __restrict__ out)
{
    int img, kg; decode_bx(blockIdx.x, img, kg);
    const int wave = threadIdx.x >> 6;
    const int lane = threadIdx.x & 63;
    const int k1b  = __builtin_amdgcn_readfirstlane(kg * 64 + wave * 16);

    const float* __restrict__ tp = T1t + (size_t)img * (HN * HN) + k1b;
    const float* __restrict__ bp = Tdf + 4 * lane;

    float4 acc[16];
    #pragma unroll
    for (int q = 0; q < 16; ++q) acc[q] = make_float4(0.f, 0.f, 0.f, 0.f);

    float4 bv = *(const float4*)bp;
    float  ts[16];
    #pragma unroll
    for (int a = 0; a < 4; ++a)
        *(float4*)&ts[4 * a] = *(const float4*)(tp + 4 * a);

    #pragma unroll 1
    for (int j = 0; j < HN - 1; ++j) {
        const float4 bc = bv;
        float tc[16];
        #pragma unroll
        for (int q = 0; q < 16; ++q) tc[q] = ts[q];
        tp += HN; bp += HN;                  // prefetch row j+1
        bv = *(const float4*)bp;
        #pragma unroll
        for (int a = 0; a < 4; ++a)
            *(float4*)&ts[4 * a] = *(const float4*)(tp + 4 * a);
        FMA16(tc, bc);
    }
    FMA16(ts, bv);                           // j = 255

    const float mean = meanp[0];
    const float stdv = stdp[0];
    float* __restrict__ O =
        out + (size_t)img * (HN * HN) + (size_t)k1b * HN + 4 * lane;
    #pragma unroll
    for (int q = 0; q < 16; ++q) {
        float4 v;
        v.x = (logf(fabsf(acc[q].x) + 1e-13f) - mean) / stdv;
        v.y = (logf(fabsf(acc[q].y) + 1e-13f) - mean) / stdv;
        v.z = (logf(fabsf(acc[q].z) + 1e-13f) - mean) / stdv;
        v.w = (logf(fabsf(acc[q].w) + 1e-13f) - mean) / stdv;
        *(float4*)(O + q * HN) = v;          // coalesced
    }
}

// ======================= fused fallback (R3, proven) =======================
#define SLAB 32
__global__ __launch_bounds__(256, 3) void dct2_f32(
    const float* __restrict__ X, const float* __restrict__ Tdf,
    const float* __restrict__ meanp, const float* __restrict__ stdp,
    float* __restrict__ out)
{
    __shared__ union SU {
        struct { float Xs[8][HN]; float CHc[8][SLAB]; } p1;
        float Bc[16][HN];
    } u;
    __shared__ float T1s[SLAB][HN + 1];

    const int t   = threadIdx.x;
    const int img = blockIdx.x >> 3;
    const int k0  = (blockIdx.x & 7) * SLAB;
    const float* __restrict__ Xi = X + (size_t)img * (HN * HN);
    const int ci = t & 7;
    const int ib = t >> 3;

    float acc[8][4];
    #pragma unroll
    for (int q = 0; q < 8; ++q)
        #pragma unroll
        for (int r = 0; r < 4; ++r) acc[q][r] = 0.0f;

    for (int i0 = 0; i0 < HN; i0 += 8) {
        {
            int rr = t >> 5, cc = (t & 31) * 4;
            float4 a = *(const float4*)(Xi + (i0 + rr) * HN + cc);
            float4 b = *(const float4*)(Xi + (i0 + rr) * HN + cc + 128);
            *(float4*)&u.p1.Xs[rr][cc]       = a;
            *(float4*)&u.p1.Xs[rr][cc + 128] = b;
            u.p1.CHc[rr][t & 31] = Tdf[(i0 + rr) * HN + k0 + (t & 31)];
        }
        __syncthreads();
        #pragma unroll
        for (int ii = 0; ii < 8; ++ii) {
            float xr[8];
            *(float4*)&xr[0] = *(const float4*)&u.p1.Xs[ii][8 * ib];
            *(float4*)&xr[4] = *(const float4*)&u.p1.Xs[ii][8 * ib + 4];
            float ch[4];
            *(float4*)&ch[0] = *(const float4*)&u.p1.CHc[ii][4 * ci];
            #pragma unroll
            for (int q = 0; q < 8; ++q)
                #pragma unroll
                for (int r = 0; r < 4; ++r)
                    acc[q][r] = fmaf(ch[r], xr[q], acc[q][r]);
        }
        __syncthreads();
    }
    #pragma unroll
    for (int q = 0; q < 8; ++q)
        #pragma unroll
        for (int r = 0; r < 4; ++r)
            T1s[4 * ci + r][8 * ib + q] = acc[q][r];
    __syncthreads();

    float acc2[8][4];
    #pragma unroll
    for (int q = 0; q < 8; ++q)
        #pragma unroll
        for (int r = 0; r < 4; ++r) acc2[q][r] = 0.0f;

    for (int j0 = 0; j0 < HN; j0 += 16) {
        #pragma unroll
        for (int rep = 0; rep < 4; ++rep) {
            int idx = rep * 1024 + t * 4;
            int p = idx >> 8, c = idx & 255;
            *(float4*)&u.Bc[p][c] = *(const float4*)(Tdf + (j0 + p) * HN + c);
        }
        __syncthreads();
        #pragma unroll
        for (int p = 0; p < 16; ++p) {
            float a[4];
            #pragma unroll
            for (int r = 0; r < 4; ++r) a[r] = T1s[4 * ci + r][j0 + p];
            float b[8];
            *(float4*)&b[0] = *(const float4*)&u.Bc[p][8 * ib];
            *(float4*)&b[4] = *(const float4*)&u.Bc[p][8 * ib + 4];
            #pragma unroll
            for (int q = 0; q < 8; ++q)
                #pragma unroll
                for (int r = 0; r < 4; ++r)
                    acc2[q][r] = fmaf(a[r], b[q], acc2[q][r]);
        }
        __syncthreads();
    }

    const float mean = meanp[0];
    const float stdv = stdp[0];
    #pragma unroll
    for (int q = 0; q < 8; ++q)
        #pragma unroll
        for (int r = 0; r < 4; ++r) {
            float v = (logf(fabsf(acc2[q][r]) + 1e-13f) - mean) / stdv;
            T1s[4 * ci + r][8 * ib + q] = v;
        }
    __syncthreads();

    float* __restrict__ O = out + (size_t)img * (HN * HN) + (size_t)k0 * HN;
    #pragma unroll
    for (int rep = 0; rep < 8; ++rep) {
        int idx = rep * 1024 + t * 4;
        int row = idx >> 8, col = idx & 255;
        float4 v = make_float4(T1s[row][col], T1s[row][col + 1],
                               T1s[row][col + 2], T1s[row][col + 3]);
        *(float4*)(O + row * HN + col) = v;
    }
}

extern "C" void kernel_launch(void* const* d_in, const int* in_sizes, int n_in,
                              void* d_out, int out_size, void* d_ws, size_t ws_size,
                              hipStream_t stream) {
    const float* X     = (const float*)d_in[0];
    const float* meanp = (const float*)d_in[1];
    const float* stdp  = (const float*)d_in[2];

    float* Tdf = (float*)d_ws;                       // 256 KB basis
    const size_t T1_OFF    = 256 * 1024;
    const size_t T1_BYTES  = (size_t)NIMG * HN * HN * sizeof(float);  // 100.7MB

    basis_init<<<256, 256, 0, stream>>>(Tdf);

    if (ws_size >= T1_OFF + T1_BYTES) {
        float* T1 = (float*)((char*)d_ws + T1_OFF);
        t1_kernel<<<NIMG * 4, 256, 0, stream>>>(X, Tdf, T1);
        y_kernel <<<NIMG * 4, 256, 0, stream>>>(T1, Tdf, meanp, stdp,
                                                (float*)d_out);
    } else {
        dct2_f32<<<NIMG * 8, 256, 0, stream>>>(X, Tdf, meanp, stdp,
                                               (float*)d_out);
    }
}

// Round 3
// 442.886 us; speedup vs baseline: 1.7796x; 1.0586x over previous
//
#include <hip/hip_runtime.h>
#include <cmath>

// out = (log(|DCT2(x)| + 1e-13) - mean) / std,  x: [384][256][256] f32.
// CORRECTNESS CONTRACT (R1-R3 evidence): reference accumulates in f32;
// near-zero DCT coefficients are f32 rounding NOISE and log() demands we
// reproduce that noise ~exactly. Every output element must be a single
// sequential fmaf chain, i ascending (stage 1) / j ascending (stage 2),
// with the stage-1 result rounded to f32. NO MFMA, NO split accumulators.
//
// R7 (from R6 counters: VALUBusy 51%, Occupancy 54%, HBM 10%):
//  - R6 allocator used >85 VGPR -> only 4 blocks/CU resident; grid is
//    6/CU -> two dispatch rounds (4 + 2 tail) and 512cy hide budget vs
//    ~900cy HBM miss. __launch_bounds__(256,6) forces <=85 VGPR: whole
//    grid co-resident (6 blocks/CU), 6 waves/SIMD hiding.
//  - prefetch depth 2 (unroll-2 rotation, loads issued BEFORE the FMA
//    block via explicit temporaries) on vector + scalar streams.
//  - y_kernel mirrored to t1's shape: vector operand = streamed T1t rows
//    (coalesced, lanes span k1), scalar = L2-hot basis. R6's y still
//    scalar-scattered the 100MB stream at 64B/1KB; now both kernels
//    stream the big operand linearly.
// Numerics bit-identical chains to the R4-R6 passing kernels.

#define HN    256
#define NIMG  384

// ---- f32 basis: Tdf[i][k] = (float)( cos(pi*(2i+1)*k/512) * s(k) ) --------
__global__ void basis_init(float* __restrict__ Tdf) {
    int idx = blockIdx.x * 256 + threadIdx.x;   // 65536
    int i = idx >> 8, k = idx & 255;
    double c = cos(M_PI * (2.0 * i + 1.0) * (double)k / 512.0);
    double s = (k == 0) ? sqrt(1.0 / 256.0) : sqrt(2.0 / 256.0);
    Tdf[idx] = (float)(c * s);
}

// blockIdx swizzle: the 4 blocks of one image land on the same XCD
// (HW round-robins consecutive workgroups across the 8 XCDs).
// n in [0,1536): img = (n&7)*48 + (n>>5), kg = (n>>3)&3. Bijective.
__device__ __forceinline__ void decode_bx(int n, int& img, int& kg) {
    img = (n & 7) * 48 + (n >> 5);
    kg  = (n >> 3) & 3;
}

// 64 fmaf: acc[q].c += S[q] * V.c   (S scalar per q, V float4 per lane)
#define FMA16(S, V) \
    _Pragma("unroll") \
    for (int q = 0; q < 16; ++q) { \
        acc[q].x = fmaf(S[q], V.x, acc[q].x); \
        acc[q].y = fmaf(S[q], V.y, acc[q].y); \
        acc[q].z = fmaf(S[q], V.z, acc[q].z); \
        acc[q].w = fmaf(S[q], V.w, acc[q].w); \
    }

#define SLOAD16(D, P) \
    _Pragma("unroll") \
    for (int a = 0; a < 4; ++a) \
        *(float4*)&(D)[4 * a] = *(const float4*)((P) + 4 * a);

// Shared main loop: acc[q] += S_q(row) * V(row), row ascending, D=2 prefetch.
// vp: per-lane vector stream (row stride HN); sp: wave-uniform scalar stream.
#define DCT_MAINLOOP(vp, sp) \
    float4 acc[16]; \
    _Pragma("unroll") \
    for (int q = 0; q < 16; ++q) acc[q] = make_float4(0.f, 0.f, 0.f, 0.f); \
    float4 xv0, xv1; float bs0[16], bs1[16]; \
    xv0 = *(const float4*)(vp); (vp) += HN; \
    xv1 = *(const float4*)(vp); (vp) += HN; \
    SLOAD16(bs0, sp); (sp) += HN; \
    SLOAD16(bs1, sp); (sp) += HN; \
    _Pragma("unroll 1") \
    for (int i = 0; i < HN - 2; i += 2) { \
        float4 xn0 = *(const float4*)(vp); (vp) += HN; \
        float sn0[16]; SLOAD16(sn0, sp); (sp) += HN; \
        FMA16(bs0, xv0); \
        xv0 = xn0; \
        _Pragma("unroll") \
        for (int q = 0; q < 16; ++q) bs0[q] = sn0[q]; \
        float4 xn1 = *(const float4*)(vp); (vp) += HN; \
        float sn1[16]; SLOAD16(sn1, sp); (sp) += HN; \
        FMA16(bs1, xv1); \
        xv1 = xn1; \
        _Pragma("unroll") \
        for (int q = 0; q < 16; ++q) bs1[q] = sn1[q]; \
    } \
    FMA16(bs0, xv0); \
    FMA16(bs1, xv1);

// ======================= two-kernel LDS-free path ==========================
// Stage 1: T1t[img][j][k1] = sum_i Tdf[i][k1] * X[img][i][j]   (i ascending)
// Block = 4 waves; wave w owns k1 slab [k1b,k1b+16), lanes span j (4/lane).
// Vector: X row i (coalesced streaming). Scalar: Tdf[i][k1b..+15] (L2-hot).
__global__ __launch_bounds__(256, 6) void t1_kernel(
    const float* __restrict__ X, const float* __restrict__ Tdf,
    float* __restrict__ T1t)
{
    int img, kg; decode_bx(blockIdx.x, img, kg);
    const int wave = threadIdx.x >> 6;
    const int lane = threadIdx.x & 63;
    const int k1b  = __builtin_amdgcn_readfirstlane(kg * 64 + wave * 16);

    const float* __restrict__ vp = X + (size_t)img * (HN * HN) + 4 * lane;
    const float* __restrict__ sp = Tdf + k1b;

    DCT_MAINLOOP(vp, sp)

    // transposed store: T1t[img][4*lane+r][k1b + 4a + 0..3]
    float* __restrict__ T1o =
        T1t + (size_t)img * (HN * HN) + (size_t)(4 * lane) * HN + k1b;
    const float* af = (const float*)acc;     // af[4*q + r]
    #pragma unroll
    for (int r = 0; r < 4; ++r)
        #pragma unroll
        for (int a = 0; a < 4; ++a) {
            float4 v = make_float4(af[4 * (4 * a + 0) + r],
                                   af[4 * (4 * a + 1) + r],
                                   af[4 * (4 * a + 2) + r],
                                   af[4 * (4 * a + 3) + r]);
            *(float4*)(T1o + r * HN + 4 * a) = v;
        }
}

// Stage 2: out[k1][k2] = sum_j T1t[j][k1] * Tdf[j][k2]   (j ascending) + epi
// Block = 4 waves; wave w owns k2 slab [k2b,k2b+16), lanes span k1 (4/lane).
// Vector: T1t row j (coalesced streaming). Scalar: Tdf[j][k2b..+15] (L2-hot).
__global__ __launch_bounds__(256, 6) void y_kernel(
    const float* __restrict__ T1t, const float* __restrict__ Tdf,
    const float* __restrict__ meanp, const float* __restrict__ stdp,
    float* __restrict__ out)
{
    int img, kg; decode_bx(blockIdx.x, img, kg);
    const int wave = threadIdx.x >> 6;
    const int lane = threadIdx.x & 63;
    const int k2b  = __builtin_amdgcn_readfirstlane(kg * 64 + wave * 16);

    const float* __restrict__ vp = T1t + (size_t)img * (HN * HN) + 4 * lane;
    const float* __restrict__ sp = Tdf + k2b;

    DCT_MAINLOOP(vp, sp)

    // epilogue + transposed store: out[img][4*lane+r][k2b + 4a + 0..3]
    const float mean = meanp[0];
    const float stdv = stdp[0];
    float* __restrict__ O =
        out + (size_t)img * (HN * HN) + (size_t)(4 * lane) * HN + k2b;
    const float* af = (const float*)acc;     // af[4*q + r]
    #pragma unroll
    for (int r = 0; r < 4; ++r)
        #pragma unroll
        for (int a = 0; a < 4; ++a) {
            float4 v;
            v.x = (logf(fabsf(af[4 * (4 * a + 0) + r]) + 1e-13f) - mean) / stdv;
            v.y = (logf(fabsf(af[4 * (4 * a + 1) + r]) + 1e-13f) - mean) / stdv;
            v.z = (logf(fabsf(af[4 * (4 * a + 2) + r]) + 1e-13f) - mean) / stdv;
            v.w = (logf(fabsf(af[4 * (4 * a + 3) + r]) + 1e-13f) - mean) / stdv;
            *(float4*)(O + r * HN + 4 * a) = v;
        }
}

// ======================= fused fallback (R3, proven) =======================
#define SLAB 32
__global__ __launch_bounds__(256, 3) void dct2_f32(
    const float* __restrict__ X, const float* __restrict__ Tdf,
    const float* __restrict__ meanp, const float* __restrict__ stdp,
    float* __restrict__ out)
{
    __shared__ union SU {
        struct { float Xs[8][HN]; float CHc[8][SLAB]; } p1;
        float Bc[16][HN];
    } u;
    __shared__ float T1s[SLAB][HN + 1];

    const int t   = threadIdx.x;
    const int img = blockIdx.x >> 3;
    const int k0  = (blockIdx.x & 7) * SLAB;
    const float* __restrict__ Xi = X + (size_t)img * (HN * HN);
    const int ci = t & 7;
    const int ib = t >> 3;

    float acc[8][4];
    #pragma unroll
    for (int q = 0; q < 8; ++q)
        #pragma unroll
        for (int r = 0; r < 4; ++r) acc[q][r] = 0.0f;

    for (int i0 = 0; i0 < HN; i0 += 8) {
        {
            int rr = t >> 5, cc = (t & 31) * 4;
            float4 a = *(const float4*)(Xi + (i0 + rr) * HN + cc);
            float4 b = *(const float4*)(Xi + (i0 + rr) * HN + cc + 128);
            *(float4*)&u.p1.Xs[rr][cc]       = a;
            *(float4*)&u.p1.Xs[rr][cc + 128] = b;
            u.p1.CHc[rr][t & 31] = Tdf[(i0 + rr) * HN + k0 + (t & 31)];
        }
        __syncthreads();
        #pragma unroll
        for (int ii = 0; ii < 8; ++ii) {
            float xr[8];
            *(float4*)&xr[0] = *(const float4*)&u.p1.Xs[ii][8 * ib];
            *(float4*)&xr[4] = *(const float4*)&u.p1.Xs[ii][8 * ib + 4];
            float ch[4];
            *(float4*)&ch[0] = *(const float4*)&u.p1.CHc[ii][4 * ci];
            #pragma unroll
            for (int q = 0; q < 8; ++q)
                #pragma unroll
                for (int r = 0; r < 4; ++r)
                    acc[q][r] = fmaf(ch[r], xr[q], acc[q][r]);
        }
        __syncthreads();
    }
    #pragma unroll
    for (int q = 0; q < 8; ++q)
        #pragma unroll
        for (int r = 0; r < 4; ++r)
            T1s[4 * ci + r][8 * ib + q] = acc[q][r];
    __syncthreads();

    float acc2[8][4];
    #pragma unroll
    for (int q = 0; q < 8; ++q)
        #pragma unroll
        for (int r = 0; r < 4; ++r) acc2[q][r] = 0.0f;

    for (int j0 = 0; j0 < HN; j0 += 16) {
        #pragma unroll
        for (int rep = 0; rep < 4; ++rep) {
            int idx = rep * 1024 + t * 4;
            int p = idx >> 8, c = idx & 255;
            *(float4*)&u.Bc[p][c] = *(const float4*)(Tdf + (j0 + p) * HN + c);
        }
        __syncthreads();
        #pragma unroll
        for (int p = 0; p < 16; ++p) {
            float a[4];
            #pragma unroll
            for (int r = 0; r < 4; ++r) a[r] = T1s[4 * ci + r][j0 + p];
            float b[8];
            *(float4*)&b[0] = *(const float4*)&u.Bc[p][8 * ib];
            *(float4*)&b[4] = *(const float4*)&u.Bc[p][8 * ib + 4];
            #pragma unroll
            for (int q = 0; q < 8; ++q)
                #pragma unroll
                for (int r = 0; r < 4; ++r)
                    acc2[q][r] = fmaf(a[r], b[q], acc2[q][r]);
        }
        __syncthreads();
    }

    const float mean = meanp[0];
    const float stdv = stdp[0];
    #pragma unroll
    for (int q = 0; q < 8; ++q)
        #pragma unroll
        for (int r = 0; r < 4; ++r) {
            float v = (logf(fabsf(acc2[q][r]) + 1e-13f) - mean) / stdv;
            T1s[4 * ci + r][8 * ib + q] = v;
        }
    __syncthreads();

    float* __restrict__ O = out + (size_t)img * (HN * HN) + (size_t)k0 * HN;
    #pragma unroll
    for (int rep = 0; rep < 8; ++rep) {
        int idx = rep * 1024 + t * 4;
        int row = idx >> 8, col = idx & 255;
        float4 v = make_float4(T1s[row][col], T1s[row][col + 1],
                               T1s[row][col + 2], T1s[row][col + 3]);
        *(float4*)(O + row * HN + col) = v;
    }
}

extern "C" void kernel_launch(void* const* d_in, const int* in_sizes, int n_in,
                              void* d_out, int out_size, void* d_ws, size_t ws_size,
                              hipStream_t stream) {
    const float* X     = (const float*)d_in[0];
    const float* meanp = (const float*)d_in[1];
    const float* stdp  = (const float*)d_in[2];

    float* Tdf = (float*)d_ws;                       // 256 KB basis
    const size_t T1_OFF    = 256 * 1024;
    const size_t T1_BYTES  = (size_t)NIMG * HN * HN * sizeof(float);  // 100.7MB

    basis_init<<<256, 256, 0, stream>>>(Tdf);

    if (ws_size >= T1_OFF + T1_BYTES) {
        float* T1 = (float*)((char*)d_ws + T1_OFF);
        t1_kernel<<<NIMG * 4, 256, 0, stream>>>(X, Tdf, T1);
        y_kernel <<<NIMG * 4, 256, 0, stream>>>(T1, Tdf, meanp, stdp,
                                                (float*)d_out);
    } else {
        dct2_f32<<<NIMG * 8, 256, 0, stream>>>(X, Tdf, meanp, stdp,
                                               (float*)d_out);
    }
}